// Round 1
// baseline (848.304 us; speedup 1.0000x reference)
//
#include <hip/hip_runtime.h>
#include <stdint.h>

#define E_NUM 16
#define T_TOK 512
#define H_DIM 2048
#define I_DIM 1408
#define K_TOP 6
#define CAP   512   // max tokens per expert (dedup guarantees <= T)

typedef __attribute__((ext_vector_type(8))) __bf16 bf16x8;
typedef __attribute__((ext_vector_type(4))) float f32x4;
typedef __attribute__((ext_vector_type(8))) unsigned short us8;

__device__ __forceinline__ unsigned short f2bf(float f) {
  union { float f; unsigned u; } v; v.f = f;
  unsigned r = v.u + 0x7FFFu + ((v.u >> 16) & 1u);   // RNE
  return (unsigned short)(r >> 16);
}

// 8 fp32 (two float4) * scale -> bf16x8 MFMA fragment
__device__ __forceinline__ bf16x8 pack8(float4 a, float4 b, float s) {
  union { us8 u; bf16x8 h; } t;
  t.u[0]=f2bf(a.x*s); t.u[1]=f2bf(a.y*s); t.u[2]=f2bf(a.z*s); t.u[3]=f2bf(a.w*s);
  t.u[4]=f2bf(b.x*s); t.u[5]=f2bf(b.y*s); t.u[6]=f2bf(b.z*s); t.u[7]=f2bf(b.w*s);
  return t.h;
}

// ---------- routing: dedup top-k, build per-expert token lists + combine weights ----------
__global__ void k_routing(const float* __restrict__ rw, const int* __restrict__ sel,
                          int* counts, int* list, float* cw) {
  int t = blockIdx.x * blockDim.x + threadIdx.x;
  if (t >= T_TOK) return;
  int e[K_TOP]; float w[K_TOP];
#pragma unroll
  for (int k = 0; k < K_TOP; ++k) { e[k] = sel[t*K_TOP+k]; w[k] = rw[t*K_TOP+k]; }
#pragma unroll
  for (int k = 0; k < K_TOP; ++k) {
    bool dup = false;
#pragma unroll
    for (int j = 0; j < K_TOP; ++j) if (j < k && e[j] == e[k]) dup = true;
    if (!dup) {
      float c = 0.f;
#pragma unroll
      for (int j = 0; j < K_TOP; ++j) if (e[j] == e[k]) c += w[j];
      int slot = atomicAdd(&counts[e[k]], 1);
      list[e[k]*CAP + slot] = t;
      cw[e[k]*CAP + slot] = c;
    }
  }
}

// ---------- x fp32 -> bf16 (2 MB, stays hot in L2/LLC for the gathers) ----------
__global__ void k_xcast(const float* __restrict__ x, unsigned short* __restrict__ xb) {
  int i = blockIdx.x * blockDim.x + threadIdx.x;   // 8 elems per thread
  const float4* src = (const float4*)x;
  float4 v0 = src[2*i], v1 = src[2*i+1];
  us8 o;
  o[0]=f2bf(v0.x); o[1]=f2bf(v0.y); o[2]=f2bf(v0.z); o[3]=f2bf(v0.w);
  o[4]=f2bf(v1.x); o[5]=f2bf(v1.y); o[6]=f2bf(v1.z); o[7]=f2bf(v1.w);
  *(us8*)(xb + (size_t)i*8) = o;
}

// ---------- fused gate+up GEMM + SwiGLU (+combine weight) -> Hbuf bf16 ----------
// Barrier-free / LDS-free: each wave owns 16 output cols (weight rows, read once,
// direct to regs, dequant in-register) x all <=256 tokens of its expert
// (acc 2x16xf32x4 = 128 VGPR). A-frags gathered per-wave from L2-resident xb.
// No __syncthreads -> no vmcnt(0) drains -> loads stay in flight, HBM-BW-bound.
__global__ __launch_bounds__(256, 2)
void k_gateup(const unsigned short* __restrict__ xb,
              const float* __restrict__ Wg, const float* __restrict__ Sg,
              const float* __restrict__ Wu, const float* __restrict__ Su,
              const int* __restrict__ counts, const int* __restrict__ list,
              const float* __restrict__ cw, unsigned short* __restrict__ Hbuf) {
  const int e   = blockIdx.y;
  const int cnt = counts[e];
  if (cnt == 0) return;
  const int tid  = threadIdx.x;
  const int wv   = tid >> 6;
  const int lane = tid & 63;
  const int quad = lane >> 4;
  const int ln   = lane & 15;
  const int nb   = blockIdx.x * 64 + wv * 16;      // wave's 16-col base in I

  const int*   listE = list + e * CAP;
  const float* cwE   = cw + e * CAP;
  const float* wgRow = Wg + (size_t)e * I_DIM * H_DIM + (size_t)(nb + ln) * H_DIM;
  const float* wuRow = Wu + (size_t)e * I_DIM * H_DIM + (size_t)(nb + ln) * H_DIM;
  const float* SgE   = Sg + e * (11*16) + (nb >> 7) * 16;   // (E, I/128, H/128)
  const float* SuE   = Su + e * (11*16) + (nb >> 7) * 16;
  unsigned short* HbE = Hbuf + (size_t)e * CAP * I_DIM;
  const char* xbB = (const char*)xb;

  for (int m0 = 0; m0 < cnt; m0 += 256) {
    const int rem   = cnt - m0;
    const int miMax = (rem >= 256) ? 16 : ((rem + 15) >> 4);   // wave-uniform
    unsigned tokoff[16];                                        // per-lane A row base (bytes)
#pragma unroll
    for (int mi = 0; mi < 16; ++mi) {
      int m = m0 + mi*16 + ln;
      tokoff[mi] = (unsigned)(listE[m < cnt ? m : 0] * (H_DIM * 2));
    }
    f32x4 accG[16], accU[16];
#pragma unroll
    for (int mi = 0; mi < 16; ++mi) {
      accG[mi] = (f32x4){0.f,0.f,0.f,0.f};
      accU[mi] = (f32x4){0.f,0.f,0.f,0.f};
    }

    for (int kc = 0; kc < H_DIM / 64; ++kc) {     // 32 K-chunks of 64
      const int k0 = kc * 64;
      const float sG = SgE[k0 >> 7];
      const float sU = SuE[k0 >> 7];
#pragma unroll
      for (int ks = 0; ks < 2; ++ks) {
        const int kk = k0 + ks*32 + quad*8;       // float/bf16 element index
        float4 g0 = *(const float4*)(wgRow + kk);
        float4 g1 = *(const float4*)(wgRow + kk + 4);
        float4 u0 = *(const float4*)(wuRow + kk);
        float4 u1 = *(const float4*)(wuRow + kk + 4);
        bf16x8 bg = pack8(g0, g1, sG);
        bf16x8 bu = pack8(u0, u1, sU);
        const unsigned ko = (unsigned)(kk * 2);
#pragma unroll
        for (int mi = 0; mi < 16; ++mi) {
          if (mi < miMax) {
            bf16x8 a = *(const bf16x8*)(xbB + tokoff[mi] + ko);
            accG[mi] = __builtin_amdgcn_mfma_f32_16x16x32_bf16(a, bg, accG[mi], 0, 0, 0);
            accU[mi] = __builtin_amdgcn_mfma_f32_16x16x32_bf16(a, bu, accU[mi], 0, 0, 0);
          }
        }
      }
    }
    // epilogue: h = silu(g) * u * combine_weight  (C/D: col=lane&15, row=quad*4+reg)
#pragma unroll
    for (int mi = 0; mi < 16; ++mi) {
      if (mi < miMax) {
#pragma unroll
        for (int r = 0; r < 4; ++r) {
          int m = m0 + mi*16 + quad*4 + r;
          if (m < cnt) {
            float c = cwE[m];
            float g = accG[mi][r];
            float u = accU[mi][r];
            float h = g / (1.f + __expf(-g)) * u * c;
            HbE[(size_t)m * I_DIM + nb + ln] = f2bf(h);
          }
        }
      }
    }
  }
}

// ---------- down GEMM + scatter-add to output ----------
// Same barrier-free structure; wave owns 32 cols of H (acc 2x16xf32x4).
// Grid decoded as e = bid&15 so experts e and e+8 pin to XCD e%8 (round-robin
// dispatch heuristic): each expert's ~1.4 MB Hbuf slice stays in one L2.
__global__ __launch_bounds__(256, 2)
void k_down(const unsigned short* __restrict__ Hbuf,
            const float* __restrict__ Wd, const float* __restrict__ Sd,
            const int* __restrict__ counts, const int* __restrict__ list,
            float* __restrict__ out) {
  const int bid  = blockIdx.x;
  const int e    = bid & 15;
  const int nblk = bid >> 4;                      // 0..15
  const int cnt  = counts[e];
  if (cnt == 0) return;
  const int tid  = threadIdx.x;
  const int wv   = tid >> 6;
  const int lane = tid & 63;
  const int quad = lane >> 4;
  const int ln   = lane & 15;
  const int nb   = nblk * 128 + wv * 32;          // wave's 32-col base in H

  const int* listE = list + e * CAP;
  const char* HbB = (const char*)(Hbuf + (size_t)e * CAP * I_DIM);
  const float* wd0 = Wd + (size_t)e * H_DIM * I_DIM + (size_t)(nb + ln) * I_DIM;
  const float* wd1 = wd0 + (size_t)16 * I_DIM;
  const float* SdE = Sd + e * (16*11) + (nb >> 7) * 11;   // (E, H/128, I/128)

  for (int m0 = 0; m0 < cnt; m0 += 256) {
    const int rem   = cnt - m0;
    const int miMax = (rem >= 256) ? 16 : ((rem + 15) >> 4);
    unsigned rowoff[16];
#pragma unroll
    for (int mi = 0; mi < 16; ++mi)
      rowoff[mi] = (unsigned)((m0 + mi*16 + ln) * (I_DIM * 2));
    f32x4 acc0[16], acc1[16];
#pragma unroll
    for (int mi = 0; mi < 16; ++mi) {
      acc0[mi] = (f32x4){0.f,0.f,0.f,0.f};
      acc1[mi] = (f32x4){0.f,0.f,0.f,0.f};
    }

    for (int kc = 0; kc < I_DIM / 64; ++kc) {     // 22 K-chunks of 64
      const int k0 = kc * 64;
      const float s = SdE[k0 >> 7];
#pragma unroll
      for (int ks = 0; ks < 2; ++ks) {
        const int kk = k0 + ks*32 + quad*8;
        float4 a0 = *(const float4*)(wd0 + kk);
        float4 a1 = *(const float4*)(wd0 + kk + 4);
        float4 c0 = *(const float4*)(wd1 + kk);
        float4 c1 = *(const float4*)(wd1 + kk + 4);
        bf16x8 b0 = pack8(a0, a1, s);
        bf16x8 b1 = pack8(c0, c1, s);
        const unsigned ko = (unsigned)(kk * 2);
#pragma unroll
        for (int mi = 0; mi < 16; ++mi) {
          if (mi < miMax) {
            bf16x8 a = *(const bf16x8*)(HbB + rowoff[mi] + ko);
            acc0[mi] = __builtin_amdgcn_mfma_f32_16x16x32_bf16(a, b0, acc0[mi], 0, 0, 0);
            acc1[mi] = __builtin_amdgcn_mfma_f32_16x16x32_bf16(a, b1, acc1[mi], 0, 0, 0);
          }
        }
      }
    }
    // epilogue: scatter-add (combine weight already folded into Hbuf)
#pragma unroll
    for (int mi = 0; mi < 16; ++mi) {
      if (mi < miMax) {
#pragma unroll
        for (int r = 0; r < 4; ++r) {
          int m = m0 + mi*16 + quad*4 + r;
          if (m < cnt) {
            int t = listE[m];
            atomicAdd(out + (size_t)t * H_DIM + nb + ln,      acc0[mi][r]);
            atomicAdd(out + (size_t)t * H_DIM + nb + 16 + ln, acc1[mi][r]);
          }
        }
      }
    }
  }
}

extern "C" void kernel_launch(void* const* d_in, const int* in_sizes, int n_in,
                              void* d_out, int out_size, void* d_ws, size_t ws_size,
                              hipStream_t stream) {
  const float* x  = (const float*)d_in[0];
  const float* Wg = (const float*)d_in[1];
  const float* Sg = (const float*)d_in[2];
  const float* Wu = (const float*)d_in[3];
  const float* Su = (const float*)d_in[4];
  const float* Wd = (const float*)d_in[5];
  const float* Sd = (const float*)d_in[6];
  const float* rw = (const float*)d_in[7];
  const int*  sel = (const int*)d_in[8];
  float* out = (float*)d_out;

  char* ws = (char*)d_ws;
  int*   counts = (int*)ws;                                   // 64 B (zeroed below)
  int*   list   = (int*)(ws + 256);                           // 32 KB
  float* cw     = (float*)(ws + 256 + 32768);                 // 32 KB
  unsigned short* xb   = (unsigned short*)(ws + 256 + 65536); // 2 MB
  unsigned short* Hbuf = (unsigned short*)(ws + 256 + 65536 + (size_t)T_TOK*H_DIM*2); // ~22 MB
  (void)in_sizes; (void)n_in; (void)out_size; (void)ws_size;

  hipMemsetAsync(counts, 0, 256, stream);
  hipMemsetAsync(out, 0, sizeof(float) * (size_t)T_TOK * H_DIM, stream);
  k_routing<<<dim3((T_TOK + 255) / 256), dim3(256), 0, stream>>>(rw, sel, counts, list, cw);
  k_xcast<<<dim3((T_TOK * H_DIM) / 2048), dim3(256), 0, stream>>>(x, xb);
  k_gateup<<<dim3(I_DIM / 64, E_NUM), dim3(256), 0, stream>>>(xb, Wg, Sg, Wu, Su, counts, list, cw, Hbuf);
  k_down<<<dim3(256), dim3(256), 0, stream>>>(Hbuf, Wd, Sd, counts, list, out);
}